// Round 15
// baseline (97.660 us; speedup 1.0000x reference)
//
#include <hip/hip_runtime.h>

#define SQRT2f 1.41421356237309515f
#define SQRT3f 1.73205080756887729f

__device__ __forceinline__ float2 cmul(float2 a, float2 b) {
  return make_float2(a.x*b.x - a.y*b.y, a.x*b.y + a.y*b.x);
}
__device__ __forceinline__ float2 cadd(float2 a, float2 b) {
  return make_float2(a.x + b.x, a.y + b.y);
}

// complex helpers on scalar re/im with float2 coefficients (out = A*a [+ B*b [+ C*c]])
#define CM1(nr,ni, A, ar,ai) { \
  nr = (A).x*(ar) - (A).y*(ai); \
  ni = (A).x*(ai) + (A).y*(ar); }
#define CM2(nr,ni, A, ar,ai, B, br,bi) { \
  nr = (A).x*(ar) - (A).y*(ai) + (B).x*(br) - (B).y*(bi); \
  ni = (A).x*(ai) + (A).y*(ar) + (B).x*(bi) + (B).y*(br); }
#define CM3(nr,ni, A, ar,ai, B, br,bi, C, cr,ci) { \
  nr = (A).x*(ar)-(A).y*(ai) + (B).x*(br)-(B).y*(bi) + (C).x*(cr)-(C).y*(ci); \
  ni = (A).x*(ai)+(A).y*(ar) + (B).x*(bi)+(B).y*(br) + (C).x*(ci)+(C).y*(cr); }

// BS 9x9 (real coefs) on one component set, q = 3*outer+inner; rows 0,8 identity
#define BSQR(p01,p10,p02,p11,p20,p12,p21, c_,s_,c2_,s2_,cc_,ss_,rcs_) { \
  float t1=p01, t3=p10; p01 = c_*t1 - s_*t3; p10 = s_*t1 + c_*t3; \
  float t2=p02, t4=p11, t6=p20; \
  p02 = cc_*t2 - rcs_*t4 + ss_*t6; \
  p11 = rcs_*t2 + c2_*t4 - rcs_*t6; \
  p20 = ss_*t2 + rcs_*t4 + cc_*t6; \
  float t5=p12, t7=p21; p12 = c2_*t5 - s2_*t7; p21 = s2_*t5 + c2_*t7; }

// ---- plain BS nonet, SoA, in place (elements 1..7 only) ----
template<int SP>
__device__ __forceinline__ void bs_soa(float* __restrict__ sR,
                                       float* __restrict__ sI,
                                       int base, float2 cs) {
  const float c = cs.x, s = cs.y;
  const float c2 = c*c - s*s, s2 = 2.f*c*s;
  const float cc = c*c, ss = s*s, rcs = SQRT2f*c*s;
  float r1 = sR[base+SP],   r3 = sR[base+3*SP];
  float r2 = sR[base+2*SP], r4 = sR[base+4*SP], r6 = sR[base+6*SP];
  float r5 = sR[base+5*SP], r7 = sR[base+7*SP];
  float i1 = sI[base+SP],   i3 = sI[base+3*SP];
  float i2 = sI[base+2*SP], i4 = sI[base+4*SP], i6 = sI[base+6*SP];
  float i5 = sI[base+5*SP], i7 = sI[base+7*SP];
  BSQR(r1,r3,r2,r4,r6,r5,r7, c,s,c2,s2,cc,ss,rcs);
  BSQR(i1,i3,i2,i4,i6,i5,i7, c,s,c2,s2,cc,ss,rcs);
  sR[base+SP]   = r1;  sR[base+3*SP] = r3;
  sR[base+2*SP] = r2;  sR[base+4*SP] = r4;  sR[base+6*SP] = r6;
  sR[base+5*SP] = r5;  sR[base+7*SP] = r7;
  sI[base+SP]   = i1;  sI[base+3*SP] = i3;
  sI[base+2*SP] = i2;  sI[base+4*SP] = i4;  sI[base+6*SP] = i6;
  sI[base+5*SP] = i5;  sI[base+7*SP] = i7;
}

// ---- fused (SQ_A outer ⊗ SQ_B inner) then BS, SoA. G = A(5),B(5) ----
template<int SP>
__device__ __forceinline__ void sqbs_soa(float* __restrict__ sR,
                                         float* __restrict__ sI,
                                         int base, const float2* __restrict__ G,
                                         float2 cs) {
  float2 A00=G[0],A02=G[1],A11=G[2],A20=G[3],A22=G[4];
  float2 B00=G[5],B02=G[6],B11=G[7],B20=G[8],B22=G[9];
  float v00r=sR[base],      v00i=sI[base];
  float v01r=sR[base+SP],   v01i=sI[base+SP];
  float v02r=sR[base+2*SP], v02i=sI[base+2*SP];
  float v10r=sR[base+3*SP], v10i=sI[base+3*SP];
  float v11r=sR[base+4*SP], v11i=sI[base+4*SP];
  float v12r=sR[base+5*SP], v12i=sI[base+5*SP];
  float v20r=sR[base+6*SP], v20i=sI[base+6*SP];
  float v21r=sR[base+7*SP], v21i=sI[base+7*SP];
  float v22r=sR[base+8*SP], v22i=sI[base+8*SP];
  // B along inner, rows 0..2
  { float n0r,n0i,n1r,n1i,n2r,n2i;
    CM2(n0r,n0i, B00,v00r,v00i, B02,v02r,v02i);
    CM1(n1r,n1i, B11,v01r,v01i);
    CM2(n2r,n2i, B20,v00r,v00i, B22,v02r,v02i);
    v00r=n0r;v00i=n0i; v01r=n1r;v01i=n1i; v02r=n2r;v02i=n2i; }
  { float n0r,n0i,n1r,n1i,n2r,n2i;
    CM2(n0r,n0i, B00,v10r,v10i, B02,v12r,v12i);
    CM1(n1r,n1i, B11,v11r,v11i);
    CM2(n2r,n2i, B20,v10r,v10i, B22,v12r,v12i);
    v10r=n0r;v10i=n0i; v11r=n1r;v11i=n1i; v12r=n2r;v12i=n2i; }
  { float n0r,n0i,n1r,n1i,n2r,n2i;
    CM2(n0r,n0i, B00,v20r,v20i, B02,v22r,v22i);
    CM1(n1r,n1i, B11,v21r,v21i);
    CM2(n2r,n2i, B20,v20r,v20i, B22,v22r,v22i);
    v20r=n0r;v20i=n0i; v21r=n1r;v21i=n1i; v22r=n2r;v22i=n2i; }
  // A along outer, cols 0..2
  { float n0r,n0i,n1r,n1i,n2r,n2i;
    CM2(n0r,n0i, A00,v00r,v00i, A02,v20r,v20i);
    CM1(n1r,n1i, A11,v10r,v10i);
    CM2(n2r,n2i, A20,v00r,v00i, A22,v20r,v20i);
    v00r=n0r;v00i=n0i; v10r=n1r;v10i=n1i; v20r=n2r;v20i=n2i; }
  { float n0r,n0i,n1r,n1i,n2r,n2i;
    CM2(n0r,n0i, A00,v01r,v01i, A02,v21r,v21i);
    CM1(n1r,n1i, A11,v11r,v11i);
    CM2(n2r,n2i, A20,v01r,v01i, A22,v21r,v21i);
    v01r=n0r;v01i=n0i; v11r=n1r;v11i=n1i; v21r=n2r;v21i=n2i; }
  { float n0r,n0i,n1r,n1i,n2r,n2i;
    CM2(n0r,n0i, A00,v02r,v02i, A02,v22r,v22i);
    CM1(n1r,n1i, A11,v12r,v12i);
    CM2(n2r,n2i, A20,v02r,v02i, A22,v22r,v22i);
    v02r=n0r;v02i=n0i; v12r=n1r;v12i=n1i; v22r=n2r;v22i=n2i; }
  const float c = cs.x, s = cs.y;
  const float c2 = c*c - s*s, s2 = 2.f*c*s;
  const float cc = c*c, ss = s*s, rcs = SQRT2f*c*s;
  BSQR(v01r,v10r,v02r,v11r,v20r,v12r,v21r, c,s,c2,s2,cc,ss,rcs);
  BSQR(v01i,v10i,v02i,v11i,v20i,v12i,v21i, c,s,c2,s2,cc,ss,rcs);
  sR[base]      = v00r; sI[base]      = v00i;
  sR[base+SP]   = v01r; sI[base+SP]   = v01i;
  sR[base+2*SP] = v02r; sI[base+2*SP] = v02i;
  sR[base+3*SP] = v10r; sI[base+3*SP] = v10i;
  sR[base+4*SP] = v11r; sI[base+4*SP] = v11i;
  sR[base+5*SP] = v12r; sI[base+5*SP] = v12i;
  sR[base+6*SP] = v20r; sI[base+6*SP] = v20i;
  sR[base+7*SP] = v21r; sI[base+7*SP] = v21i;
  sR[base+8*SP] = v22r; sI[base+8*SP] = v22i;
}

// ---- fused (DPK_A outer ⊗ DPK_B inner, dense) then BS, SoA. G = A(9),B(9) ----
template<int SP>
__device__ __forceinline__ void dpbs_soa(float* __restrict__ sR,
                                         float* __restrict__ sI,
                                         int base, const float2* __restrict__ G,
                                         float2 cs) {
  float v00r=sR[base],      v00i=sI[base];
  float v01r=sR[base+SP],   v01i=sI[base+SP];
  float v02r=sR[base+2*SP], v02i=sI[base+2*SP];
  float v10r=sR[base+3*SP], v10i=sI[base+3*SP];
  float v11r=sR[base+4*SP], v11i=sI[base+4*SP];
  float v12r=sR[base+5*SP], v12i=sI[base+5*SP];
  float v20r=sR[base+6*SP], v20i=sI[base+6*SP];
  float v21r=sR[base+7*SP], v21i=sI[base+7*SP];
  float v22r=sR[base+8*SP], v22i=sI[base+8*SP];
  {
    float2 B0=G[9],B1=G[10],B2=G[11],B3=G[12],B4=G[13],B5=G[14],B6=G[15],B7=G[16],B8=G[17];
    { float n0r,n0i,n1r,n1i,n2r,n2i;
      CM3(n0r,n0i, B0,v00r,v00i, B1,v01r,v01i, B2,v02r,v02i);
      CM3(n1r,n1i, B3,v00r,v00i, B4,v01r,v01i, B5,v02r,v02i);
      CM3(n2r,n2i, B6,v00r,v00i, B7,v01r,v01i, B8,v02r,v02i);
      v00r=n0r;v00i=n0i; v01r=n1r;v01i=n1i; v02r=n2r;v02i=n2i; }
    { float n0r,n0i,n1r,n1i,n2r,n2i;
      CM3(n0r,n0i, B0,v10r,v10i, B1,v11r,v11i, B2,v12r,v12i);
      CM3(n1r,n1i, B3,v10r,v10i, B4,v11r,v11i, B5,v12r,v12i);
      CM3(n2r,n2i, B6,v10r,v10i, B7,v11r,v11i, B8,v12r,v12i);
      v10r=n0r;v10i=n0i; v11r=n1r;v11i=n1i; v12r=n2r;v12i=n2i; }
    { float n0r,n0i,n1r,n1i,n2r,n2i;
      CM3(n0r,n0i, B0,v20r,v20i, B1,v21r,v21i, B2,v22r,v22i);
      CM3(n1r,n1i, B3,v20r,v20i, B4,v21r,v21i, B5,v22r,v22i);
      CM3(n2r,n2i, B6,v20r,v20i, B7,v21r,v21i, B8,v22r,v22i);
      v20r=n0r;v20i=n0i; v21r=n1r;v21i=n1i; v22r=n2r;v22i=n2i; }
  }
  {
    float2 A0=G[0],A1=G[1],A2=G[2],A3=G[3],A4=G[4],A5=G[5],A6=G[6],A7=G[7],A8=G[8];
    { float n0r,n0i,n1r,n1i,n2r,n2i;
      CM3(n0r,n0i, A0,v00r,v00i, A1,v10r,v10i, A2,v20r,v20i);
      CM3(n1r,n1i, A3,v00r,v00i, A4,v10r,v10i, A5,v20r,v20i);
      CM3(n2r,n2i, A6,v00r,v00i, A7,v10r,v10i, A8,v20r,v20i);
      v00r=n0r;v00i=n0i; v10r=n1r;v10i=n1i; v20r=n2r;v20i=n2i; }
    { float n0r,n0i,n1r,n1i,n2r,n2i;
      CM3(n0r,n0i, A0,v01r,v01i, A1,v11r,v11i, A2,v21r,v21i);
      CM3(n1r,n1i, A3,v01r,v01i, A4,v11r,v11i, A5,v21r,v21i);
      CM3(n2r,n2i, A6,v01r,v01i, A7,v11r,v11i, A8,v21r,v21i);
      v01r=n0r;v01i=n0i; v11r=n1r;v11i=n1i; v21r=n2r;v21i=n2i; }
    { float n0r,n0i,n1r,n1i,n2r,n2i;
      CM3(n0r,n0i, A0,v02r,v02i, A1,v12r,v12i, A2,v22r,v22i);
      CM3(n1r,n1i, A3,v02r,v02i, A4,v12r,v12i, A5,v22r,v22i);
      CM3(n2r,n2i, A6,v02r,v02i, A7,v12r,v12i, A8,v22r,v22i);
      v02r=n0r;v02i=n0i; v12r=n1r;v12i=n1i; v22r=n2r;v22i=n2i; }
  }
  const float c = cs.x, s = cs.y;
  const float c2 = c*c - s*s, s2 = 2.f*c*s;
  const float cc = c*c, ss = s*s, rcs = SQRT2f*c*s;
  BSQR(v01r,v10r,v02r,v11r,v20r,v12r,v21r, c,s,c2,s2,cc,ss,rcs);
  BSQR(v01i,v10i,v02i,v11i,v20i,v12i,v21i, c,s,c2,s2,cc,ss,rcs);
  sR[base]      = v00r; sI[base]      = v00i;
  sR[base+SP]   = v01r; sI[base+SP]   = v01i;
  sR[base+2*SP] = v02r; sI[base+2*SP] = v02i;
  sR[base+3*SP] = v10r; sI[base+3*SP] = v10i;
  sR[base+4*SP] = v11r; sI[base+4*SP] = v11i;
  sR[base+5*SP] = v12r; sI[base+5*SP] = v12i;
  sR[base+6*SP] = v20r; sI[base+6*SP] = v20i;
  sR[base+7*SP] = v21r; sI[base+7*SP] = v21i;
  sR[base+8*SP] = v22r; sI[base+8*SP] = v22i;
}

#define BASE4(g, s0,s1,s2,s3) ({ int _d=(g); int _b=(_d%3)*(s0); _d/=3; \
  _b += (_d%3)*(s1); _d/=3; _b += (_d%3)*(s2); _d/=3; _b += (_d%3)*(s3); _b; })
#define BASE5(g, s0,s1,s2,s3,s4) ({ int _d=(g); int _b=(_d%3)*(s0); _d/=3; \
  _b += (_d%3)*(s1); _d/=3; _b += (_d%3)*(s2); _d/=3; _b += (_d%3)*(s3); _d/=3; \
  _b += (_d%3)*(s4); _b; })

// DPK(L,mode)[i][j] = Kerr_i * U_disp[i][j] * phase^j (th2-layer phases)
__device__ __forceinline__ float2 dpk_entry(const float* __restrict__ dr,
                                            const float* __restrict__ th2,
                                            const float* __restrict__ kp,
                                            int L, int mode, int i, int j) {
  float sn, cn; sincosf(SQRT3f*dr[L*6+mode], &sn, &cn);
  float sw = sn*(1.f/SQRT3f), cw = (1.f-cn)*(1.f/3.f);
  float U;
  if      (i==0) U = (j==0) ? (1.f-cw)     : (j==1) ? (-sw)         : (SQRT2f*cw);
  else if (i==1) U = (j==0) ? (sw)         : (j==1) ? (1.f-3.f*cw)  : (-SQRT2f*sw);
  else           U = (j==0) ? (SQRT2f*cw)  : (j==1) ? (SQRT2f*sw)   : (1.f-2.f*cw);
  float2 ph = make_float2(1.f, 0.f);
  if (mode < 5) { float ps, pc; sincosf(th2[L*35+29+mode], &ps, &pc);
                  ph = make_float2(pc, ps); }
  float2 phj = (j==0) ? make_float2(1.f,0.f) : (j==1) ? ph : cmul(ph, ph);
  float ks, kc; sincosf(0.001f*kp[L*6+mode], &ks, &kc);
  float2 k1 = make_float2(kc, ks);
  float2 ki = (i==0) ? make_float2(1.f,0.f)
            : (i==1) ? k1 : cmul(cmul(k1,k1), cmul(k1,k1));
  float2 t = cmul(phj, ki);
  return make_float2(U*t.x, U*t.y);
}

// gtab (float2):
// [0,180)   BS (c,s): idx = (L*2+pass)*15 + pos (application order)
// [180,360) SQG: 180 + L*30 + c*10 : A(5) mode 2c, B(5) mode 2c+1 (th1 phases)
// [360,630) DPG: 360 + Ls*54 + c*18 : A(9) mode 2c, B(9) mode 2c+1 (layers 0..4)
// [630,684) Meas M_m = DPK(5,m)† X3 DPK(5,m): 630 + m*9 + i*3+j
// [684,690) init disp (sw,cw) per mode
__global__ __launch_bounds__(128)
void cvnn_kernel(const float* __restrict__ x,
                 const float* __restrict__ th1,
                 const float* __restrict__ th2,
                 const float* __restrict__ sr,
                 const float* __restrict__ dr,
                 const float* __restrict__ kp,
                 float* __restrict__ out) {
  __shared__ float sR[729];
  __shared__ float sI[729];
  __shared__ float2 gtab[690];
  __shared__ float red[12];

  const int tid = threadIdx.x;
  const int bidx = blockIdx.x;

  // ---- build gate table ----
  for (int f = tid; f < 690; f += 128) {
    float sn, cn; float2 v;
    if (f < 180) {
      int Lp = f/15, pos = f%15;
      int L = Lp/2, pass = Lp%2;
      float th = (pass ? th2 : th1)[L*35 + pos];
      sincosf(th, &sn, &cn); v = make_float2(cn, sn);
    } else if (f < 360) {
      int i = f - 180; int Lc = i/10, e = i%10;
      int L = Lc/3, c3 = Lc%3;
      int mode = 2*c3 + (e >= 5); int ee = e%5;
      float Sq, Cq; sincosf(0.25f*SQRT2f*sr[L*6+mode], &Sq, &Cq);
      float2 ph = make_float2(1.f, 0.f);
      if (mode < 5) { float ps, pc; sincosf(th1[L*35+29+mode], &ps, &pc);
                      ph = make_float2(pc, ps); }
      float2 ph2 = cmul(ph, ph);
      if      (ee == 0) v = make_float2(Cq, 0.f);
      else if (ee == 1) v = make_float2(Sq*ph2.x, Sq*ph2.y);
      else if (ee == 2) v = ph;
      else if (ee == 3) v = make_float2(-Sq, 0.f);
      else              v = make_float2(Cq*ph2.x, Cq*ph2.y);
    } else if (f < 630) {
      int i = f - 360; int Ld = i/18, e = i%18;
      int Ls = Ld/3, c3 = Ld%3;
      int mode = 2*c3 + (e >= 9); int ee = e%9;
      v = dpk_entry(dr, th2, kp, Ls, mode, ee/3, ee%3);
    } else if (f < 684) {
      int i = f - 630; int m = i/9, e = i%9;
      int ii = e/3, jj = e%3;
      float2 D0i = dpk_entry(dr, th2, kp, 5, m, 0, ii);
      float2 D1i = dpk_entry(dr, th2, kp, 5, m, 1, ii);
      float2 D2i = dpk_entry(dr, th2, kp, 5, m, 2, ii);
      float2 D0j = dpk_entry(dr, th2, kp, 5, m, 0, jj);
      float2 D1j = dpk_entry(dr, th2, kp, 5, m, 1, jj);
      float2 D2j = dpk_entry(dr, th2, kp, 5, m, 2, jj);
      float2 c0 = make_float2(D0i.x, -D0i.y);
      float2 c1 = make_float2(D1i.x, -D1i.y);
      float2 c2 = make_float2(D2i.x, -D2i.y);
      float2 acc = cmul(c0, D1j);
      float2 tmp = make_float2(D0j.x + SQRT2f*D2j.x, D0j.y + SQRT2f*D2j.y);
      acc = cadd(acc, cmul(c1, tmp));
      acc = cadd(acc, cmul(c2, make_float2(SQRT2f*D1j.x, SQRT2f*D1j.y)));
      v = acc;
    } else {
      int mode = f - 684;
      sincosf(SQRT3f*x[bidx*6 + mode], &sn, &cn);
      v = make_float2(sn*(1.f/SQRT3f), (1.f-cn)*(1.f/3.f));
    }
    gtab[f] = v;
  }
  __syncthreads();

  // ---- init: product state of displaced |0> ----
  for (int idx = tid; idx < 729; idx += 128) {
    float pr = 1.f; int d = idx;
#pragma unroll
    for (int mm = 5; mm >= 0; --mm) {
      int n = d % 3; d /= 3;
      float2 dc = gtab[684 + mm];
      pr *= (n==0) ? (1.f-dc.y) : (n==1) ? dc.x : SQRT2f*dc.y;
    }
    sR[idx] = pr;
    sI[idx] = 0.f;
  }

  // ---- per-thread nonet bases: one nonet per active thread (tid < 81) ----
  const bool act = (tid < 81);
  const int g = (tid < 81) ? tid : 0;
  const int b0 = g;                          // k=0 SP=81
  const int b1 = BASE4(g, 1, 3, 9, 243);     // k=1 SP=27
  const int b2 = BASE4(g, 1, 3, 81, 243);    // k=2 SP=9
  const int b3 = BASE4(g, 1, 27, 81, 243);   // k=3 SP=3
  const int b4 = BASE4(g, 9, 27, 81, 243);   // k=4 SP=1
  __syncthreads();

  float2 csN = gtab[0];   // prefetch first sweep's (c,s)
  __syncthreads();

#define BSP(SP, BB, NEXT)  { if (act) bs_soa<SP>(sR, sI, BB, csN); \
    csN = gtab[NEXT]; __syncthreads(); }
#define DPBS(SP, BB, GI, NEXT) { if (act) dpbs_soa<SP>(sR, sI, BB, &gtab[GI], csN); \
    csN = gtab[NEXT]; __syncthreads(); }
#define SQBS(SP, BB, GI, NEXT) { if (act) sqbs_soa<SP>(sR, sI, BB, &gtab[GI], csN); \
    csN = gtab[NEXT]; __syncthreads(); }

#pragma unroll
  for (int L = 0; L < 6; ++L) {
    const int i1 = (L*2)*15, i2 = (L*2+1)*15;
    // pass 1: first course folds previous layer's DPK (L>=1)
    if (L == 0) {
      BSP(81, b0, i1+1); BSP(9, b2, i1+2); BSP(1, b4, i1+3);
    } else {
      const int gd = 360 + (L-1)*54;
      DPBS(81, b0, gd+0,  i1+1); DPBS(9, b2, gd+18, i1+2); DPBS(1, b4, gd+36, i1+3);
    }
    BSP(27, b1, i1+4);  BSP(3, b3, i1+5);
    BSP(81, b0, i1+6);  BSP(9, b2, i1+7);  BSP(1, b4, i1+8);
    BSP(27, b1, i1+9);  BSP(3, b3, i1+10);
    BSP(81, b0, i1+11); BSP(9, b2, i1+12); BSP(1, b4, i1+13);
    BSP(27, b1, i1+14); BSP(3, b3, i2+0);
    // pass 2: first course folds this layer's SQ (+th1 phases)
    {
      const int gs = 180 + L*30;
      SQBS(81, b0, gs+0, i2+1); SQBS(9, b2, gs+10, i2+2); SQBS(1, b4, gs+20, i2+3);
    }
    BSP(27, b1, i2+4);  BSP(3, b3, i2+5);
    BSP(81, b0, i2+6);  BSP(9, b2, i2+7);  BSP(1, b4, i2+8);
    BSP(27, b1, i2+9);  BSP(3, b3, i2+10);
    BSP(81, b0, i2+11); BSP(9, b2, i2+12); BSP(1, b4, i2+13);
    BSP(27, b1, i2+14); BSP(3, b3, (L < 5) ? (L+1)*30 : 0);
  }

  // ---- <X_m> via folded Hermitian M_m = DPK(5,m)† X DPK(5,m) ----
  float xs[6] = {0.f,0.f,0.f,0.f,0.f,0.f};
  for (int it = 0; it < 2; ++it) {
    int t = tid + (it << 7);
    if (t < 243) {
#define XACC(m, SS, BB) { int b_ = (BB); \
      const float2* M_ = &gtab[630 + (m)*9]; \
      float d0 = M_[0].x, d1 = M_[4].x, d2 = M_[8].x; \
      float2 M01 = M_[1], M02 = M_[2], M12 = M_[5]; \
      float ar_ = sR[b_], ai_ = sI[b_]; \
      float er_ = sR[b_+(SS)], ei_ = sI[b_+(SS)]; \
      float fr_ = sR[b_+2*(SS)], fi_ = sI[b_+2*(SS)]; \
      xs[m] += d0*(ar_*ar_ + ai_*ai_) + d1*(er_*er_ + ei_*ei_) \
             + d2*(fr_*fr_ + fi_*fi_) \
        + 2.f*(M01.x*(ar_*er_ + ai_*ei_) - M01.y*(ar_*ei_ - ai_*er_)) \
        + 2.f*(M02.x*(ar_*fr_ + ai_*fi_) - M02.y*(ar_*fi_ - ai_*fr_)) \
        + 2.f*(M12.x*(er_*fr_ + ei_*fi_) - M12.y*(er_*fi_ - ei_*fr_)); }
      XACC(0, 243, BASE5(t, 1, 3, 9, 27, 81));
      XACC(1, 81,  BASE5(t, 1, 3, 9, 27, 243));
      XACC(2, 27,  BASE5(t, 1, 3, 9, 81, 243));
      XACC(3, 9,   BASE5(t, 1, 3, 27, 81, 243));
      XACC(4, 3,   BASE5(t, 1, 9, 27, 81, 243));
      XACC(5, 1,   BASE5(t, 3, 9, 27, 81, 243));
    }
  }
  const int wid = tid >> 6;
#pragma unroll
  for (int m = 0; m < 6; ++m) {
    float v = xs[m];
    for (int off = 32; off > 0; off >>= 1) v += __shfl_down(v, off);
    if ((tid & 63) == 0) red[wid*6 + m] = v;
  }
  __syncthreads();
  if (tid < 6) out[bidx*6 + tid] = red[tid] + red[6 + tid];
}

extern "C" void kernel_launch(void* const* d_in, const int* in_sizes, int n_in,
                              void* d_out, int out_size, void* d_ws, size_t ws_size,
                              hipStream_t stream) {
  const float* x  = (const float*)d_in[0];
  const float* t1 = (const float*)d_in[1];
  const float* t2 = (const float*)d_in[2];
  const float* sr = (const float*)d_in[3];
  const float* dr = (const float*)d_in[4];
  const float* kp = (const float*)d_in[5];
  const int B = in_sizes[0] / 6;
  cvnn_kernel<<<B, 128, 0, stream>>>(x, t1, t2, sr, dr, kp, (float*)d_out);
}